// Round 13
// baseline (292.527 us; speedup 1.0000x reference)
//
#include <hip/hip_runtime.h>

#define DIM 2048
#define NH 16
#define HD 128
#define BB 2
#define LL 2048
#define MROWS (BB * LL)   // 4096
#define NKV 2304          // 2048 q + 128 k + 128 v
#define NT 32             // K=2048 / BK=64 for both big GEMMs

typedef __attribute__((ext_vector_type(8))) short short8;
typedef __attribute__((ext_vector_type(4))) float floatx4;

__device__ inline ushort f2bf(float f) {
    union { float f; unsigned u; } v; v.f = f;
    unsigned r = v.u + 0x7FFFu + ((v.u >> 16) & 1u);
    return (ushort)(r >> 16);
}

// native RNE f32->bf16 (1 VALU op vs 3 for the bit-twiddle; same rounding)
__device__ __forceinline__ ushort f2bf_fast(float f) {
    __bf16 h = (__bf16)f;
    return __builtin_bit_cast(unsigned short, h);
}

#define GL16(g, l)                                                         \
    __builtin_amdgcn_global_load_lds(                                      \
        (const __attribute__((address_space(1))) unsigned int*)(g),        \
        (__attribute__((address_space(3))) unsigned int*)(l), 16, 0, 0)

__device__ __forceinline__ short8 ld8(const ushort* p) {
    return *reinterpret_cast<const short8*>(p);
}

// ---------------------------------------------------------------------------
// fused prep: conv_bf16 (blocks 0..4095) + weight transpose (4096..6271).
// ---------------------------------------------------------------------------
__global__ __launch_bounds__(256) void prep(const float* __restrict__ x,
                                            ushort* __restrict__ xb,
                                            const float* __restrict__ Wq,
                                            const float* __restrict__ Wk,
                                            const float* __restrict__ Wv,
                                            const float* __restrict__ Wo,
                                            ushort* __restrict__ Wcatt,
                                            ushort* __restrict__ Wot) {
    __shared__ ushort T[64][72];
    const int bid = blockIdx.x;
    const int tid = threadIdx.x;
    if (bid < 4096) {
        size_t i = ((size_t)bid * 256 + tid) * 8;
        float4 a = *reinterpret_cast<const float4*>(x + i);
        float4 b = *reinterpret_cast<const float4*>(x + i + 4);
        ushort o[8] = {f2bf(a.x), f2bf(a.y), f2bf(a.z), f2bf(a.w),
                       f2bf(b.x), f2bf(b.y), f2bf(b.z), f2bf(b.w)};
        *reinterpret_cast<uint4*>(xb + i) = *reinterpret_cast<uint4*>(o);
        return;
    }
    const int wb = bid - 4096;
    const float* in;
    ushort* out;
    int in_ld, c0, r0;
    const int out_ld = 2048;
    if (wb < 1024) {
        in = Wq; out = Wcatt; in_ld = 2048;
        c0 = (wb & 31) * 64; r0 = (wb >> 5) * 64;
    } else if (wb < 2048) {
        int t = wb - 1024;
        in = Wo; out = Wot; in_ld = 2048;
        c0 = (t & 31) * 64; r0 = (t >> 5) * 64;
    } else if (wb < 2112) {
        int t = wb - 2048;
        in = Wk; out = Wcatt + (size_t)2048 * 2048; in_ld = 128;
        c0 = (t & 1) * 64; r0 = (t >> 1) * 64;
    } else {
        int t = wb - 2112;
        in = Wv; out = Wcatt + (size_t)2176 * 2048; in_ld = 128;
        c0 = (t & 1) * 64; r0 = (t >> 1) * 64;
    }
#pragma unroll
    for (int rep = 0; rep < 4; ++rep) {
        int idx = tid + rep * 256;
        int r = idx >> 4, c4 = idx & 15;
        float4 f = *reinterpret_cast<const float4*>(
            in + (size_t)(r0 + r) * in_ld + c0 + c4 * 4);
        T[r][c4 * 4 + 0] = f2bf(f.x);
        T[r][c4 * 4 + 1] = f2bf(f.y);
        T[r][c4 * 4 + 2] = f2bf(f.z);
        T[r][c4 * 4 + 3] = f2bf(f.w);
    }
    __syncthreads();
#pragma unroll
    for (int rep = 0; rep < 4; ++rep) {
        int idx = tid + rep * 256;
        int cr = idx >> 4, rc4 = idx & 15;
        uint a0 = (uint)T[rc4 * 4 + 0][cr] | ((uint)T[rc4 * 4 + 1][cr] << 16);
        uint a1 = (uint)T[rc4 * 4 + 2][cr] | ((uint)T[rc4 * 4 + 3][cr] << 16);
        uint2 val = {a0, a1};
        *reinterpret_cast<uint2*>(
            out + (size_t)(c0 + cr) * out_ld + r0 + rc4 * 4) = val;
    }
}

// ---------------------------------------------------------------------------
// 128x128 bf16 GEMM (QKV): 2-phase one-barrier schedule, 256 threads /
// 4 waves (2Mx2N, 64x64 per wave), LDS 64 KiB (2 dbuf x [A 16K | B 16K])
// -> 2 blocks/CU. Grid (18,32) = 576 blocks: 512 resident = ALL 256 CUs
// busy (the 256^2 variant ran 144 blocks = 56% coverage; per-busy-CU rate
// was already 3.44 TF so coverage is the multiplier). XOR chunk swizzle
// (identical 128B row stride + ^sel read -> 0 conflicts, carried over).
// XCD rect swizzle: per XCD a 9bx x 8by rectangle (bijective for 18x32).
// waves_per_eu(2,2): 256-VGPR budget, ~140 live, no spill (R4 lesson).
// ---------------------------------------------------------------------------
__global__ __launch_bounds__(256)
__attribute__((amdgpu_waves_per_eu(2, 2)))
void gemm2p128(const ushort* __restrict__ A,
               const ushort* __restrict__ Bt,
               float* __restrict__ Y, int N) {
    __shared__ __attribute__((aligned(16))) ushort lds[32768];  // 64 KiB
    const int tid = threadIdx.x;
    const int lane = tid & 63;
    const int w = tid >> 6;             // 4 waves
    const int wm = w >> 1, wn = w & 1;  // 2M x 2N
    const int col = lane & 15, quad = lane >> 4;
    const int sel = col & 7;
    // XCD rect swizzle: L%8 = XCD; XCD x8 owns bx in [9*(x8&1),+9) x
    // by in [8*(x8>>1),+8). Bijective for 576 blocks.
    const int L = blockIdx.y * 18 + blockIdx.x;
    const int x8 = L & 7, jj = L >> 3;  // jj in [0,72)
    const int bx = (x8 & 1) * 9 + jj % 9;
    const int by = (x8 >> 1) * 8 + jj / 9;
    const int m0 = by * 128, n0 = bx * 128;

    // staging: per unit 1024 slots (8 ushorts); slot s = tid + rep*256;
    // row = s>>3 (rep adds 32 rows, row&7 invariant), chunk=(s&7)^(row&7)
    const int r0 = tid >> 3;
    const int gc0 = (tid & 7) ^ (r0 & 7);
    const uint offA = (uint)(m0 + r0) * 2048u + (uint)gc0 * 8u;
    const uint offB = (uint)(n0 + r0) * 2048u + (uint)gc0 * 8u;

    floatx4 acc[4][4];
#pragma unroll
    for (int mt = 0; mt < 4; ++mt)
#pragma unroll
        for (int nt = 0; nt < 4; ++nt) acc[mt][nt] = (floatx4){0.f, 0.f, 0.f, 0.f};

    const int aoff0 = wm * 4096 + col * 64;         // A rows wm*64+mt*16+col
    const int boff0 = 8192 + wn * 4096 + col * 64;  // B rows wn*64+nt*16+col
    const int koff0 = (quad ^ sel) * 8;
    const int koff1 = ((4 + quad) ^ sel) * 8;

    auto stage = [&](ushort* lbase, int t) {
        if (t >= NT) return;
        uint tk = (uint)t * 64u;
#pragma unroll
        for (int rep = 0; rep < 4; ++rep) {
            GL16(A + offA + rep * 65536u + tk,
                 lbase + (size_t)(tid + rep * 256) * 8);
            GL16(Bt + offB + rep * 65536u + tk,
                 lbase + 8192 + (size_t)(tid + rep * 256) * 8);
        }
    };

    stage(lds, 0);
    asm volatile("s_waitcnt vmcnt(0)" ::: "memory");
    __builtin_amdgcn_s_barrier();

#pragma unroll 2
    for (int t = 0; t < NT; ++t) {
        ushort* lb = lds + (t & 1) * 16384;
        ushort* lbn = lds + ((t + 1) & 1) * 16384;

        // ---- Ph0: k0-half reads; stage tile t+1 -> lbn; 16 MFMA ----
        short8 a0[4], b0[4];
#pragma unroll
        for (int mt = 0; mt < 4; ++mt)
            a0[mt] = ld8(lb + aoff0 + mt * 1024 + koff0);
#pragma unroll
        for (int nt = 0; nt < 4; ++nt)
            b0[nt] = ld8(lb + boff0 + nt * 1024 + koff0);
        stage(lbn, t + 1);
        __builtin_amdgcn_s_setprio(1);
#pragma unroll
        for (int mt = 0; mt < 4; ++mt)
#pragma unroll
            for (int nt = 0; nt < 4; ++nt)
                acc[mt][nt] = __builtin_amdgcn_mfma_f32_16x16x32_bf16(
                    a0[mt], b0[nt], acc[mt][nt], 0, 0, 0);
        __builtin_amdgcn_s_setprio(0);

        // ---- Ph1: k1-half reads; 16 MFMA; tile-end gate ----
        short8 a1[4], b1[4];
#pragma unroll
        for (int mt = 0; mt < 4; ++mt)
            a1[mt] = ld8(lb + aoff0 + mt * 1024 + koff1);
#pragma unroll
        for (int nt = 0; nt < 4; ++nt)
            b1[nt] = ld8(lb + boff0 + nt * 1024 + koff1);
        __builtin_amdgcn_s_setprio(1);
#pragma unroll
        for (int mt = 0; mt < 4; ++mt)
#pragma unroll
            for (int nt = 0; nt < 4; ++nt)
                acc[mt][nt] = __builtin_amdgcn_mfma_f32_16x16x32_bf16(
                    a1[mt], b1[nt], acc[mt][nt], 0, 0, 0);
        __builtin_amdgcn_s_setprio(0);
        asm volatile("s_waitcnt vmcnt(0)" ::: "memory");
        __builtin_amdgcn_s_barrier();
    }

    // epilogue: C write (m89 C/D mapping)
#pragma unroll
    for (int mt = 0; mt < 4; ++mt)
#pragma unroll
        for (int nt = 0; nt < 4; ++nt)
#pragma unroll
            for (int rr = 0; rr < 4; ++rr)
                Y[(size_t)(m0 + wm * 64 + mt * 16 + quad * 4 + rr) * N + n0 +
                  wn * 64 + nt * 16 + col] = acc[mt][nt][rr];
}

// ---------------------------------------------------------------------------
// 128x256 bf16 GEMM (out-proj): 2-phase, grid (8,32)=256 blocks = 1/CU.
// XCD rectangle swizzle (R12, proven).
// ---------------------------------------------------------------------------
template <int U>
__device__ __forceinline__ void stage_po(const ushort* __restrict__ A,
                                         const ushort* __restrict__ Bt,
                                         ushort* lbase, uint offA, uint offB,
                                         int t) {
    if (t >= NT) return;
    const ushort* g = (U < 2) ? Bt : A;
    uint off = ((U < 2) ? offB : offA) + ((U == 1) ? 128u * 2048u : 0u) +
               (uint)t * 64u;
    ushort* l = lbase + U * 8192;
    GL16(g + off, l + (size_t)threadIdx.x * 8);
    GL16(g + off + 64u * 2048u, l + (size_t)(threadIdx.x + 512) * 8);
}

__global__ __launch_bounds__(512)
__attribute__((amdgpu_waves_per_eu(2, 2)))
void gemm2pw(const ushort* __restrict__ A,
             const ushort* __restrict__ Bt,
             float* __restrict__ Y, int N) {
    __shared__ __attribute__((aligned(16))) ushort lds[49152];  // 96 KiB
    const int tid = threadIdx.x;
    const int lane = tid & 63;
    const int w = tid >> 6;
    const int wm = w >> 2, wn = w & 3;  // 2M x 4N waves
    const int col = lane & 15, quad = lane >> 4;
    const int sel = col & 7;
    // XCD rectangle swizzle: grid (8,32), 256 blocks; XCD x8 -> rect
    // (bx in [4*(x8&1), +4), by in [8*(x8>>1), +8)). Bijective.
    const int L = blockIdx.y * 8 + blockIdx.x;
    const int x8 = L & 7, jj = L >> 3;
    const int bx = (x8 & 1) * 4 + (jj & 3);
    const int by = (x8 >> 1) * 8 + (jj >> 2);
    const int m0 = by * 128, n0 = bx * 256;

    const int r0 = tid >> 3;
    const int gc0 = (tid & 7) ^ (r0 & 7);
    const uint offA = (uint)(m0 + r0) * 2048u + (uint)gc0 * 8u;
    const uint offB = (uint)(n0 + r0) * 2048u + (uint)gc0 * 8u;

    floatx4 acc[4][4];
#pragma unroll
    for (int mt = 0; mt < 4; ++mt)
#pragma unroll
        for (int nt = 0; nt < 4; ++nt) acc[mt][nt] = (floatx4){0.f, 0.f, 0.f, 0.f};

    const int aoff0 = 16384 + wm * 4096 + col * 64;
    const int boff0 = (wn >> 1) * 8192 + ((wn & 1) * 64 + col) * 64;
    const int koff0 = (quad ^ sel) * 8;
    const int koff1 = ((4 + quad) ^ sel) * 8;

    stage_po<0>(A, Bt, lds, offA, offB, 0);
    stage_po<1>(A, Bt, lds, offA, offB, 0);
    stage_po<2>(A, Bt, lds, offA, offB, 0);
    asm volatile("s_waitcnt vmcnt(0)" ::: "memory");
    __builtin_amdgcn_s_barrier();

#pragma unroll 2
    for (int t = 0; t < NT; ++t) {
        ushort* lb = lds + (t & 1) * 24576;
        ushort* lbn = lds + ((t + 1) & 1) * 24576;

        short8 a0[4], b0[4];
#pragma unroll
        for (int mt = 0; mt < 4; ++mt)
            a0[mt] = ld8(lb + aoff0 + mt * 1024 + koff0);
#pragma unroll
        for (int nt = 0; nt < 4; ++nt)
            b0[nt] = ld8(lb + boff0 + nt * 1024 + koff0);
        stage_po<0>(A, Bt, lbn, offA, offB, t + 1);
        stage_po<1>(A, Bt, lbn, offA, offB, t + 1);
        stage_po<2>(A, Bt, lbn, offA, offB, t + 1);
        __builtin_amdgcn_s_setprio(1);
#pragma unroll
        for (int mt = 0; mt < 4; ++mt)
#pragma unroll
            for (int nt = 0; nt < 4; ++nt)
                acc[mt][nt] = __builtin_amdgcn_mfma_f32_16x16x32_bf16(
                    a0[mt], b0[nt], acc[mt][nt], 0, 0, 0);
        __builtin_amdgcn_s_setprio(0);

        short8 a1[4], b1[4];
#pragma unroll
        for (int mt = 0; mt < 4; ++mt)
            a1[mt] = ld8(lb + aoff0 + mt * 1024 + koff1);
#pragma unroll
        for (int nt = 0; nt < 4; ++nt)
            b1[nt] = ld8(lb + boff0 + nt * 1024 + koff1);
        __builtin_amdgcn_s_setprio(1);
#pragma unroll
        for (int mt = 0; mt < 4; ++mt)
#pragma unroll
            for (int nt = 0; nt < 4; ++nt)
                acc[mt][nt] = __builtin_amdgcn_mfma_f32_16x16x32_bf16(
                    a1[mt], b1[nt], acc[mt][nt], 0, 0, 0);
        __builtin_amdgcn_s_setprio(0);
        asm volatile("s_waitcnt vmcnt(0)" ::: "memory");
        __builtin_amdgcn_s_barrier();
    }

#pragma unroll
    for (int mt = 0; mt < 4; ++mt)
#pragma unroll
        for (int nt = 0; nt < 4; ++nt)
#pragma unroll
            for (int rr = 0; rr < 4; ++rr)
                Y[(size_t)(m0 + wm * 64 + mt * 16 + quad * 4 + rr) * N + n0 +
                  wn * 64 + nt * 16 + col] = acc[mt][nt][rr];
}

// ---------------------------------------------------------------------------
// fused RoPE+RMSNorm (q,k) + V transpose.
// ---------------------------------------------------------------------------
__device__ __forceinline__ void rope_row(const float* __restrict__ in,
                                         ushort* __restrict__ outb,
                                         const float* __restrict__ cosb,
                                         const float* __restrict__ sinb,
                                         int row, int heads, int in_ld,
                                         int lane) {
    int token = row / heads, head = row % heads;
    int l = token & (LL - 1);
    const float* p = in + (size_t)token * in_ld + head * HD;
    float x1 = p[lane];
    float x2 = p[lane + 64];
    float c = cosb[l * 64 + lane];
    float s = sinb[l * 64 + lane];
    float o1 = x1 * c + x2 * s;
    float o2 = -x1 * s + x2 * c;
    float ss = o1 * o1 + o2 * o2;
#pragma unroll
    for (int off = 32; off > 0; off >>= 1) ss += __shfl_xor(ss, off);
    float r = rsqrtf(ss * (1.0f / 128.0f) + 1e-6f);
    outb[(size_t)row * HD + lane] = f2bf(o1 * r);
    outb[(size_t)row * HD + lane + 64] = f2bf(o2 * r);
}

__global__ __launch_bounds__(256) void rope_vt(const float* __restrict__ qkv,
                                               ushort* __restrict__ qb,
                                               ushort* __restrict__ kb,
                                               ushort* __restrict__ vt,
                                               const float* __restrict__ cosb,
                                               const float* __restrict__ sinb) {
    __shared__ ushort T[64][72];
    const int bid = blockIdx.x;
    const int tid = threadIdx.x;
    const int lane = tid & 63;
    if (bid < 16384) {
        int row = bid * 4 + (tid >> 6);
        rope_row(qkv, qb, cosb, sinb, row, NH, NKV, lane);
        return;
    }
    if (bid < 17408) {
        int row = (bid - 16384) * 4 + (tid >> 6);
        rope_row(qkv + DIM, kb, cosb, sinb, row, 1, NKV, lane);
        return;
    }
    // vtrans: 128 blocks
    const int t = bid - 17408;
    const int l0 = (t & 31) * 64, d0 = ((t >> 5) & 1) * 64, b = t >> 6;
    const float* v = qkv + DIM + HD;
#pragma unroll
    for (int rep = 0; rep < 4; ++rep) {
        int idx = tid + rep * 256;
        int r = idx >> 4, c4 = idx & 15;
        float4 f = *reinterpret_cast<const float4*>(
            v + (size_t)(b * LL + l0 + r) * NKV + d0 + c4 * 4);
        T[r][c4 * 4 + 0] = f2bf(f.x);
        T[r][c4 * 4 + 1] = f2bf(f.y);
        T[r][c4 * 4 + 2] = f2bf(f.z);
        T[r][c4 * 4 + 3] = f2bf(f.w);
    }
    __syncthreads();
#pragma unroll
    for (int rep = 0; rep < 4; ++rep) {
        int idx = tid + rep * 256;
        int dr = idx >> 4, lc4 = idx & 15;
        uint a0 = (uint)T[lc4 * 4 + 0][dr] | ((uint)T[lc4 * 4 + 1][dr] << 16);
        uint a1 = (uint)T[lc4 * 4 + 2][dr] | ((uint)T[lc4 * 4 + 3][dr] << 16);
        uint2 val = {a0, a1};
        *reinterpret_cast<uint2*>(
            vt + (size_t)(b * HD + d0 + dr) * LL + l0 + lc4 * 4) = val;
    }
}

// ---------------------------------------------------------------------------
// Flash-style causal MQA attention (R10/R12 proven best: 512 uniform paired
// blocks = 2 blocks/CU, 4 waves x 16 q-rows, single-buffer staging,
// fixed-max softmax, native bf16 cvt, diagonal-only mask, Ps stride 68,
// setprio around MFMA).
// ---------------------------------------------------------------------------
__global__ __launch_bounds__(256) void flash_mfma(const ushort* __restrict__ qb,
                                                  const ushort* __restrict__ kb,
                                                  const ushort* __restrict__ vt,
                                                  ushort* __restrict__ aob) {
    __shared__ ushort Ks[64 * 128];    // 16 KB, swizzled 16B chunks
    __shared__ ushort VTs[128 * 64];   // 16 KB, swizzled 16B chunks
    __shared__ ushort Ps[4][16][68];   // 8.5 KB, per-wave P buffer

    const int tid = threadIdx.x;
    const int w = tid >> 6, lane = tid & 63;
    const int col = lane & 15, quad = lane >> 4;
    const int pairIdx = blockIdx.x, bh = blockIdx.y;
    const int b = bh >> 4, h = bh & 15;
    const int sel = col & 7;
    const float scl2 = 0.08838834764831845f * 1.44269504088896340736f;
    const float M2 = 11.5f * 1.44269504088896340736f;

    const int ksr[4] = {(tid + 0) >> 4, (tid + 256) >> 4, (tid + 512) >> 4,
                        (tid + 768) >> 4};
    const int vsr[4] = {(tid + 0) >> 3, (tid + 256) >> 3, (tid + 512) >> 3,
                        (tid + 768) >> 3};

    for (int sp = 0; sp < 2; ++sp) {
        const int qt = sp ? (31 - pairIdx) : pairIdx;
        const int q0 = qt * 64;

        const ushort* qrow =
            qb + ((size_t)(b * LL + q0 + w * 16 + col) * NH + h) * HD;
        short8 aq[4];
#pragma unroll
        for (int kc = 0; kc < 4; ++kc)
            aq[kc] = *reinterpret_cast<const short8*>(qrow + kc * 32 + quad * 8);

        float lrow[4] = {0.f, 0.f, 0.f, 0.f};
        floatx4 oacc[8];
#pragma unroll
        for (int dt = 0; dt < 8; ++dt) oacc[dt] = (floatx4){0.f, 0.f, 0.f, 0.f};

        const int ntiles = qt + 1;
        for (int kt = 0; kt < ntiles; ++kt) {
            const int k0 = kt * 64;
            __syncthreads();
#pragma unroll
            for (int rep = 0; rep < 4; ++rep) {
                int slot = tid + rep * 256;
                int r = ksr[rep];
                int gc = (slot & 15) ^ (r & 7);
                GL16(kb + (size_t)(b * LL + k0 + r) * HD + gc * 8,
                     Ks + (size_t)slot * 8);
            }
#pragma unroll
            for (int rep = 0; rep < 4; ++rep) {
                int slot = tid + rep * 256;
                int r = vsr[rep];
                int gc = (slot & 7) ^ (r & 7);
                GL16(vt + (size_t)(b * HD + r) * LL + k0 + gc * 8,
                     VTs + (size_t)slot * 8);
            }
            __syncthreads();

            floatx4 sacc[4];
#pragma unroll
            for (int nt = 0; nt < 4; ++nt)
                sacc[nt] = (floatx4){0.f, 0.f, 0.f, 0.f};
            __builtin_amdgcn_s_setprio(1);
#pragma unroll
            for (int nt = 0; nt < 4; ++nt) {
#pragma unroll
                for (int kc = 0; kc < 4; ++kc) {
                    short8 bk = *reinterpret_cast<const short8*>(
                        &Ks[(nt * 16 + col) * 128 +
                            ((kc * 4 + quad) ^ sel) * 8]);
                    sacc[nt] = __builtin_amdgcn_mfma_f32_16x16x32_bf16(
                        aq[kc], bk, sacc[nt], 0, 0, 0);
                }
            }
            __builtin_amdgcn_s_setprio(0);

            float psum[4] = {0.f, 0.f, 0.f, 0.f};
            if (kt == qt) {
#pragma unroll
                for (int nt = 0; nt < 4; ++nt) {
                    int kj = k0 + nt * 16 + col;
#pragma unroll
                    for (int rr = 0; rr < 4; ++rr) {
                        int qi = q0 + w * 16 + quad * 4 + rr;
                        float p = exp2f(fmaf(sacc[nt][rr], scl2, -M2));
                        p = (kj <= qi) ? p : 0.0f;
                        sacc[nt][rr] = p;
                        psum[rr] += p;
                    }
                }
            } else {
#pragma unroll
                for (int nt = 0; nt < 4; ++nt)
#pragma unroll
                    for (int rr = 0; rr < 4; ++rr) {
                        float p = exp2f(fmaf(sacc[nt][rr], scl2, -M2));
                        sacc[nt][rr] = p;
                        psum[rr] += p;
                    }
            }
#pragma unroll
            for (int rr = 0; rr < 4; ++rr) lrow[rr] += psum[rr];

#pragma unroll
            for (int nt = 0; nt < 4; ++nt)
#pragma unroll
                for (int rr = 0; rr < 4; ++rr)
                    Ps[w][quad * 4 + rr][nt * 16 + col] =
                        f2bf_fast(sacc[nt][rr]);
            asm volatile("s_waitcnt lgkmcnt(0)" ::: "memory");

#pragma unroll
            for (int kt2 = 0; kt2 < 2; ++kt2) {
                short8 ap = *reinterpret_cast<const short8*>(
                    &Ps[w][col][kt2 * 32 + quad * 8]);
                __builtin_amdgcn_s_setprio(1);
#pragma unroll
                for (int dt = 0; dt < 8; ++dt) {
                    short8 bv = *reinterpret_cast<const short8*>(
                        &VTs[(dt * 16 + col) * 64 +
                             ((kt2 * 4 + quad) ^ sel) * 8]);
                    oacc[dt] = __builtin_amdgcn_mfma_f32_16x16x32_bf16(
                        ap, bv, oacc[dt], 0, 0, 0);
                }
                __builtin_amdgcn_s_setprio(0);
            }
        }

#pragma unroll
        for (int off = 1; off < 16; off <<= 1)
#pragma unroll
            for (int rr = 0; rr < 4; ++rr)
                lrow[rr] += __shfl_xor(lrow[rr], off);
        float inv[4];
#pragma unroll
        for (int rr = 0; rr < 4; ++rr) inv[rr] = 1.0f / lrow[rr];
#pragma unroll
        for (int dt = 0; dt < 8; ++dt)
#pragma unroll
            for (int rr = 0; rr < 4; ++rr)
                aob[((size_t)(b * LL + q0 + w * 16 + quad * 4 + rr) * NH + h) *
                        HD + dt * 16 + col] =
                    f2bf_fast(oacc[dt][rr] * inv[rr]);
    }
}

// ---------------------------------------------------------------------------
extern "C" void kernel_launch(void* const* d_in, const int* in_sizes, int n_in,
                              void* d_out, int out_size, void* d_ws,
                              size_t ws_size, hipStream_t stream) {
    const float* x    = (const float*)d_in[0];
    const float* cosb = (const float*)d_in[1];
    const float* sinb = (const float*)d_in[2];
    const float* Wq   = (const float*)d_in[3];
    const float* Wk   = (const float*)d_in[4];
    const float* Wv   = (const float*)d_in[5];
    const float* Wo   = (const float*)d_in[6];
    float* out = (float*)d_out;

    float* qkv  = (float*)d_ws;                         // M*2304 f32
    ushort* xb  = (ushort*)(qkv + (size_t)MROWS * NKV); // M*DIM bf16
    ushort* qb  = xb + (size_t)MROWS * DIM;             // M*DIM bf16
    ushort* kb  = qb + (size_t)MROWS * DIM;             // M*HD bf16
    ushort* vt  = kb + (size_t)MROWS * HD;              // M*HD bf16 (B,D,L)
    ushort* aob = vt + (size_t)MROWS * HD;              // M*DIM bf16
    ushort* Wcatt = aob + (size_t)MROWS * DIM;          // 2304*2048 bf16
    ushort* Wot   = Wcatt + (size_t)NKV * DIM;          // 2048*2048 bf16

    // fused input-cast + weight prep
    prep<<<dim3(4096 + 2176), 256, 0, stream>>>(x, xb, Wq, Wk, Wv, Wo, Wcatt,
                                                Wot);

    // fused q|k|v projection: (M,2048) @ (2048,2304), 128^2 x 576 blocks
    gemm2p128<<<dim3(NKV / 128, MROWS / 128), 256, 0, stream>>>(xb, Wcatt,
                                                                qkv, NKV);

    // fused RoPE+RMSNorm (q,k) + V transpose
    rope_vt<<<dim3(16384 + 1024 + 128), 256, 0, stream>>>(qkv, qb, kb, vt,
                                                          cosb, sinb);

    // causal MQA attention: 512 uniform paired blocks (qt, 31-qt)
    flash_mfma<<<dim3(LL / 128, BB * NH), 256, 0, stream>>>(qb, kb, vt, aob);

    // output projection: (M,2048) @ (2048,2048), 128x256 + XCD swz
    gemm2pw<<<dim3(DIM / 256, MROWS / 128), 512, 0, stream>>>(aob, Wot, out,
                                                              DIM);
}

// Round 14
// 267.283 us; speedup vs baseline: 1.0944x; 1.0944x over previous
//
#include <hip/hip_runtime.h>

#define DIM 2048
#define NH 16
#define HD 128
#define BB 2
#define LL 2048
#define MROWS (BB * LL)   // 4096
#define NKV 2304          // 2048 q + 128 k + 128 v
#define NT 32             // K=2048 / BK=64 for both big GEMMs

typedef __attribute__((ext_vector_type(8))) short short8;
typedef __attribute__((ext_vector_type(4))) float floatx4;

__device__ inline ushort f2bf(float f) {
    union { float f; unsigned u; } v; v.f = f;
    unsigned r = v.u + 0x7FFFu + ((v.u >> 16) & 1u);
    return (ushort)(r >> 16);
}

// native RNE f32->bf16 (1 VALU op vs 3 for the bit-twiddle; same rounding)
__device__ __forceinline__ ushort f2bf_fast(float f) {
    __bf16 h = (__bf16)f;
    return __builtin_bit_cast(unsigned short, h);
}

#define GL16(g, l)                                                         \
    __builtin_amdgcn_global_load_lds(                                      \
        (const __attribute__((address_space(1))) unsigned int*)(g),        \
        (__attribute__((address_space(3))) unsigned int*)(l), 16, 0, 0)

__device__ __forceinline__ short8 ld8(const ushort* p) {
    return *reinterpret_cast<const short8*>(p);
}

// ---------------------------------------------------------------------------
// fused prep: conv_bf16 (blocks 0..4095) + weight transpose (4096..6271).
// ---------------------------------------------------------------------------
__global__ __launch_bounds__(256) void prep(const float* __restrict__ x,
                                            ushort* __restrict__ xb,
                                            const float* __restrict__ Wq,
                                            const float* __restrict__ Wk,
                                            const float* __restrict__ Wv,
                                            const float* __restrict__ Wo,
                                            ushort* __restrict__ Wcatt,
                                            ushort* __restrict__ Wot) {
    __shared__ ushort T[64][72];
    const int bid = blockIdx.x;
    const int tid = threadIdx.x;
    if (bid < 4096) {
        size_t i = ((size_t)bid * 256 + tid) * 8;
        float4 a = *reinterpret_cast<const float4*>(x + i);
        float4 b = *reinterpret_cast<const float4*>(x + i + 4);
        ushort o[8] = {f2bf(a.x), f2bf(a.y), f2bf(a.z), f2bf(a.w),
                       f2bf(b.x), f2bf(b.y), f2bf(b.z), f2bf(b.w)};
        *reinterpret_cast<uint4*>(xb + i) = *reinterpret_cast<uint4*>(o);
        return;
    }
    const int wb = bid - 4096;
    const float* in;
    ushort* out;
    int in_ld, c0, r0;
    const int out_ld = 2048;
    if (wb < 1024) {
        in = Wq; out = Wcatt; in_ld = 2048;
        c0 = (wb & 31) * 64; r0 = (wb >> 5) * 64;
    } else if (wb < 2048) {
        int t = wb - 1024;
        in = Wo; out = Wot; in_ld = 2048;
        c0 = (t & 31) * 64; r0 = (t >> 5) * 64;
    } else if (wb < 2112) {
        int t = wb - 2048;
        in = Wk; out = Wcatt + (size_t)2048 * 2048; in_ld = 128;
        c0 = (t & 1) * 64; r0 = (t >> 1) * 64;
    } else {
        int t = wb - 2112;
        in = Wv; out = Wcatt + (size_t)2176 * 2048; in_ld = 128;
        c0 = (t & 1) * 64; r0 = (t >> 1) * 64;
    }
#pragma unroll
    for (int rep = 0; rep < 4; ++rep) {
        int idx = tid + rep * 256;
        int r = idx >> 4, c4 = idx & 15;
        float4 f = *reinterpret_cast<const float4*>(
            in + (size_t)(r0 + r) * in_ld + c0 + c4 * 4);
        T[r][c4 * 4 + 0] = f2bf(f.x);
        T[r][c4 * 4 + 1] = f2bf(f.y);
        T[r][c4 * 4 + 2] = f2bf(f.z);
        T[r][c4 * 4 + 3] = f2bf(f.w);
    }
    __syncthreads();
#pragma unroll
    for (int rep = 0; rep < 4; ++rep) {
        int idx = tid + rep * 256;
        int cr = idx >> 4, rc4 = idx & 15;
        uint a0 = (uint)T[rc4 * 4 + 0][cr] | ((uint)T[rc4 * 4 + 1][cr] << 16);
        uint a1 = (uint)T[rc4 * 4 + 2][cr] | ((uint)T[rc4 * 4 + 3][cr] << 16);
        uint2 val = {a0, a1};
        *reinterpret_cast<uint2*>(
            out + (size_t)(c0 + cr) * out_ld + r0 + rc4 * 4) = val;
    }
}

// ---------------------------------------------------------------------------
// 256x144 bf16 GEMM (QKV): 2-phase one-barrier schedule. Grid 16x16 = 256
// blocks = EXACTLY 1/CU, 100% coverage, uniform (vs 144 blocks / 56% for
// 256^2; R13 showed 128^2's per-CU-rate loss eats coverage - this keeps the
// 2-phase schedule and 64-deep K-tiles). 512 threads = 8 waves (8M x 1N),
// per-wave 32x144 output (acc[2][9]). LDS 100 KiB: 2 dbuf x [A 32K | B 18K].
// B staging is ragged (18KB = 2.25 rounds of 512x16B): third round tid<128
// (wave-uniform); chunk swizzle invariant under +64/+128 rows.
// XOR chunk swizzle -> 0 bank conflicts (B-read pattern = 256^2 case).
// XCD rect swizzle: XCD x8 owns bx in [8*(x8&1),+8) x by in [4*(x8>>1),+4).
// waves_per_eu(2,2): 256-VGPR budget (~136 live, no spill).
// ---------------------------------------------------------------------------
__global__ __launch_bounds__(512)
__attribute__((amdgpu_waves_per_eu(2, 2)))
void gemm2pq(const ushort* __restrict__ A,
             const ushort* __restrict__ Bt,
             float* __restrict__ Y, int N) {
    __shared__ __attribute__((aligned(16))) ushort lds[51200];  // 100 KiB
    const int tid = threadIdx.x;
    const int lane = tid & 63;
    const int w = tid >> 6;  // 8 waves, 8M x 1N
    const int col = lane & 15, quad = lane >> 4;
    const int sel = col & 7;
    // XCD rect swizzle (grid 16x16, 256 blocks)
    const int L = blockIdx.y * 16 + blockIdx.x;
    const int x8 = L & 7, jj = L >> 3;  // jj in [0,32)
    const int bx = (x8 & 1) * 8 + (jj & 7);
    const int by = (x8 >> 1) * 4 + (jj >> 3);
    const int m0 = by * 256, n0 = bx * 144;

    // staging: slot s = tid + rep*512; row = s>>3, chunk = (s&7)^(row&7);
    // row&7 invariant under rep (+64 rows) and the B tail (+128 rows).
    const int r0 = tid >> 3;
    const int gc0 = (tid & 7) ^ (r0 & 7);
    const uint offA = (uint)(m0 + r0) * 2048u + (uint)gc0 * 8u;
    const uint offB = (uint)(n0 + r0) * 2048u + (uint)gc0 * 8u;

    floatx4 acc[2][9];
#pragma unroll
    for (int mt = 0; mt < 2; ++mt)
#pragma unroll
        for (int nt = 0; nt < 9; ++nt) acc[mt][nt] = (floatx4){0.f, 0.f, 0.f, 0.f};

    const int aoff0 = w * 2048 + col * 64;   // A rows w*32 + mt*16 + col
    const int boff0 = 16384 + col * 64;      // B rows nt*16 + col
    const int koff0 = (quad ^ sel) * 8;
    const int koff1 = ((4 + quad) ^ sel) * 8;

    auto stage = [&](ushort* lbase, int t) {
        if (t >= NT) return;
        uint tk = (uint)t * 64u;
#pragma unroll
        for (int rep = 0; rep < 4; ++rep)
            GL16(A + offA + rep * 131072u + tk,
                 lbase + (size_t)(tid + rep * 512) * 8);
#pragma unroll
        for (int rep = 0; rep < 2; ++rep)
            GL16(Bt + offB + rep * 131072u + tk,
                 lbase + 16384 + (size_t)(tid + rep * 512) * 8);
        if (tid < 128)
            GL16(Bt + offB + 262144u + tk,
                 lbase + 16384 + (size_t)(tid + 1024) * 8);
    };

    stage(lds, 0);
    asm volatile("s_waitcnt vmcnt(0)" ::: "memory");
    __builtin_amdgcn_s_barrier();

#pragma unroll 2
    for (int t = 0; t < NT; ++t) {
        ushort* lb = lds + (t & 1) * 25600;
        ushort* lbn = lds + ((t + 1) & 1) * 25600;

        // ---- Ph0: k0-half reads (2 A + 9 B); stage t+1 -> lbn; 18 MFMA ----
        short8 a0[2], b0[9];
#pragma unroll
        for (int mt = 0; mt < 2; ++mt)
            a0[mt] = ld8(lb + aoff0 + mt * 1024 + koff0);
#pragma unroll
        for (int nt = 0; nt < 9; ++nt)
            b0[nt] = ld8(lb + boff0 + nt * 1024 + koff0);
        stage(lbn, t + 1);
        __builtin_amdgcn_s_setprio(1);
#pragma unroll
        for (int mt = 0; mt < 2; ++mt)
#pragma unroll
            for (int nt = 0; nt < 9; ++nt)
                acc[mt][nt] = __builtin_amdgcn_mfma_f32_16x16x32_bf16(
                    a0[mt], b0[nt], acc[mt][nt], 0, 0, 0);
        __builtin_amdgcn_s_setprio(0);

        // ---- Ph1: k1-half reads; 18 MFMA; tile-end gate ----
        short8 a1[2], b1[9];
#pragma unroll
        for (int mt = 0; mt < 2; ++mt)
            a1[mt] = ld8(lb + aoff0 + mt * 1024 + koff1);
#pragma unroll
        for (int nt = 0; nt < 9; ++nt)
            b1[nt] = ld8(lb + boff0 + nt * 1024 + koff1);
        __builtin_amdgcn_s_setprio(1);
#pragma unroll
        for (int mt = 0; mt < 2; ++mt)
#pragma unroll
            for (int nt = 0; nt < 9; ++nt)
                acc[mt][nt] = __builtin_amdgcn_mfma_f32_16x16x32_bf16(
                    a1[mt], b1[nt], acc[mt][nt], 0, 0, 0);
        __builtin_amdgcn_s_setprio(0);
        asm volatile("s_waitcnt vmcnt(0)" ::: "memory");
        __builtin_amdgcn_s_barrier();
    }

    // epilogue: C write (m89 C/D mapping)
#pragma unroll
    for (int mt = 0; mt < 2; ++mt)
#pragma unroll
        for (int nt = 0; nt < 9; ++nt)
#pragma unroll
            for (int rr = 0; rr < 4; ++rr)
                Y[(size_t)(m0 + w * 32 + mt * 16 + quad * 4 + rr) * N + n0 +
                  nt * 16 + col] = acc[mt][nt][rr];
}

// ---------------------------------------------------------------------------
// 128x256 bf16 GEMM (out-proj): 2-phase, grid (8,32)=256 blocks = 1/CU.
// XCD rectangle swizzle (R12, proven).
// ---------------------------------------------------------------------------
template <int U>
__device__ __forceinline__ void stage_po(const ushort* __restrict__ A,
                                         const ushort* __restrict__ Bt,
                                         ushort* lbase, uint offA, uint offB,
                                         int t) {
    if (t >= NT) return;
    const ushort* g = (U < 2) ? Bt : A;
    uint off = ((U < 2) ? offB : offA) + ((U == 1) ? 128u * 2048u : 0u) +
               (uint)t * 64u;
    ushort* l = lbase + U * 8192;
    GL16(g + off, l + (size_t)threadIdx.x * 8);
    GL16(g + off + 64u * 2048u, l + (size_t)(threadIdx.x + 512) * 8);
}

__global__ __launch_bounds__(512)
__attribute__((amdgpu_waves_per_eu(2, 2)))
void gemm2pw(const ushort* __restrict__ A,
             const ushort* __restrict__ Bt,
             float* __restrict__ Y, int N) {
    __shared__ __attribute__((aligned(16))) ushort lds[49152];  // 96 KiB
    const int tid = threadIdx.x;
    const int lane = tid & 63;
    const int w = tid >> 6;
    const int wm = w >> 2, wn = w & 3;  // 2M x 4N waves
    const int col = lane & 15, quad = lane >> 4;
    const int sel = col & 7;
    const int L = blockIdx.y * 8 + blockIdx.x;
    const int x8 = L & 7, jj = L >> 3;
    const int bx = (x8 & 1) * 4 + (jj & 3);
    const int by = (x8 >> 1) * 8 + (jj >> 2);
    const int m0 = by * 128, n0 = bx * 256;

    const int r0 = tid >> 3;
    const int gc0 = (tid & 7) ^ (r0 & 7);
    const uint offA = (uint)(m0 + r0) * 2048u + (uint)gc0 * 8u;
    const uint offB = (uint)(n0 + r0) * 2048u + (uint)gc0 * 8u;

    floatx4 acc[4][4];
#pragma unroll
    for (int mt = 0; mt < 4; ++mt)
#pragma unroll
        for (int nt = 0; nt < 4; ++nt) acc[mt][nt] = (floatx4){0.f, 0.f, 0.f, 0.f};

    const int aoff0 = 16384 + wm * 4096 + col * 64;
    const int boff0 = (wn >> 1) * 8192 + ((wn & 1) * 64 + col) * 64;
    const int koff0 = (quad ^ sel) * 8;
    const int koff1 = ((4 + quad) ^ sel) * 8;

    stage_po<0>(A, Bt, lds, offA, offB, 0);
    stage_po<1>(A, Bt, lds, offA, offB, 0);
    stage_po<2>(A, Bt, lds, offA, offB, 0);
    asm volatile("s_waitcnt vmcnt(0)" ::: "memory");
    __builtin_amdgcn_s_barrier();

#pragma unroll 2
    for (int t = 0; t < NT; ++t) {
        ushort* lb = lds + (t & 1) * 24576;
        ushort* lbn = lds + ((t + 1) & 1) * 24576;

        short8 a0[4], b0[4];
#pragma unroll
        for (int mt = 0; mt < 4; ++mt)
            a0[mt] = ld8(lb + aoff0 + mt * 1024 + koff0);
#pragma unroll
        for (int nt = 0; nt < 4; ++nt)
            b0[nt] = ld8(lb + boff0 + nt * 1024 + koff0);
        stage_po<0>(A, Bt, lbn, offA, offB, t + 1);
        stage_po<1>(A, Bt, lbn, offA, offB, t + 1);
        stage_po<2>(A, Bt, lbn, offA, offB, t + 1);
        __builtin_amdgcn_s_setprio(1);
#pragma unroll
        for (int mt = 0; mt < 4; ++mt)
#pragma unroll
            for (int nt = 0; nt < 4; ++nt)
                acc[mt][nt] = __builtin_amdgcn_mfma_f32_16x16x32_bf16(
                    a0[mt], b0[nt], acc[mt][nt], 0, 0, 0);
        __builtin_amdgcn_s_setprio(0);

        short8 a1[4], b1[4];
#pragma unroll
        for (int mt = 0; mt < 4; ++mt)
            a1[mt] = ld8(lb + aoff0 + mt * 1024 + koff1);
#pragma unroll
        for (int nt = 0; nt < 4; ++nt)
            b1[nt] = ld8(lb + boff0 + nt * 1024 + koff1);
        __builtin_amdgcn_s_setprio(1);
#pragma unroll
        for (int mt = 0; mt < 4; ++mt)
#pragma unroll
            for (int nt = 0; nt < 4; ++nt)
                acc[mt][nt] = __builtin_amdgcn_mfma_f32_16x16x32_bf16(
                    a1[mt], b1[nt], acc[mt][nt], 0, 0, 0);
        __builtin_amdgcn_s_setprio(0);
        asm volatile("s_waitcnt vmcnt(0)" ::: "memory");
        __builtin_amdgcn_s_barrier();
    }

#pragma unroll
    for (int mt = 0; mt < 4; ++mt)
#pragma unroll
        for (int nt = 0; nt < 4; ++nt)
#pragma unroll
            for (int rr = 0; rr < 4; ++rr)
                Y[(size_t)(m0 + wm * 64 + mt * 16 + quad * 4 + rr) * N + n0 +
                  wn * 64 + nt * 16 + col] = acc[mt][nt][rr];
}

// ---------------------------------------------------------------------------
// fused RoPE+RMSNorm (q,k) + V transpose.
// ---------------------------------------------------------------------------
__device__ __forceinline__ void rope_row(const float* __restrict__ in,
                                         ushort* __restrict__ outb,
                                         const float* __restrict__ cosb,
                                         const float* __restrict__ sinb,
                                         int row, int heads, int in_ld,
                                         int lane) {
    int token = row / heads, head = row % heads;
    int l = token & (LL - 1);
    const float* p = in + (size_t)token * in_ld + head * HD;
    float x1 = p[lane];
    float x2 = p[lane + 64];
    float c = cosb[l * 64 + lane];
    float s = sinb[l * 64 + lane];
    float o1 = x1 * c + x2 * s;
    float o2 = -x1 * s + x2 * c;
    float ss = o1 * o1 + o2 * o2;
#pragma unroll
    for (int off = 32; off > 0; off >>= 1) ss += __shfl_xor(ss, off);
    float r = rsqrtf(ss * (1.0f / 128.0f) + 1e-6f);
    outb[(size_t)row * HD + lane] = f2bf(o1 * r);
    outb[(size_t)row * HD + lane + 64] = f2bf(o2 * r);
}

__global__ __launch_bounds__(256) void rope_vt(const float* __restrict__ qkv,
                                               ushort* __restrict__ qb,
                                               ushort* __restrict__ kb,
                                               ushort* __restrict__ vt,
                                               const float* __restrict__ cosb,
                                               const float* __restrict__ sinb) {
    __shared__ ushort T[64][72];
    const int bid = blockIdx.x;
    const int tid = threadIdx.x;
    const int lane = tid & 63;
    if (bid < 16384) {
        int row = bid * 4 + (tid >> 6);
        rope_row(qkv, qb, cosb, sinb, row, NH, NKV, lane);
        return;
    }
    if (bid < 17408) {
        int row = (bid - 16384) * 4 + (tid >> 6);
        rope_row(qkv + DIM, kb, cosb, sinb, row, 1, MROWS == 0 ? 1 : 1, lane),
            rope_row(qkv + DIM, kb, cosb, sinb, row, 1, NKV, lane);
        return;
    }
    // vtrans: 128 blocks
    const int t = bid - 17408;
    const int l0 = (t & 31) * 64, d0 = ((t >> 5) & 1) * 64, b = t >> 6;
    const float* v = qkv + DIM + HD;
#pragma unroll
    for (int rep = 0; rep < 4; ++rep) {
        int idx = tid + rep * 256;
        int r = idx >> 4, c4 = idx & 15;
        float4 f = *reinterpret_cast<const float4*>(
            v + (size_t)(b * LL + l0 + r) * NKV + d0 + c4 * 4);
        T[r][c4 * 4 + 0] = f2bf(f.x);
        T[r][c4 * 4 + 1] = f2bf(f.y);
        T[r][c4 * 4 + 2] = f2bf(f.z);
        T[r][c4 * 4 + 3] = f2bf(f.w);
    }
    __syncthreads();
#pragma unroll
    for (int rep = 0; rep < 4; ++rep) {
        int idx = tid + rep * 256;
        int dr = idx >> 4, lc4 = idx & 15;
        uint a0 = (uint)T[lc4 * 4 + 0][dr] | ((uint)T[lc4 * 4 + 1][dr] << 16);
        uint a1 = (uint)T[lc4 * 4 + 2][dr] | ((uint)T[lc4 * 4 + 3][dr] << 16);
        uint2 val = {a0, a1};
        *reinterpret_cast<uint2*>(
            vt + (size_t)(b * HD + d0 + dr) * LL + l0 + lc4 * 4) = val;
    }
}

// ---------------------------------------------------------------------------
// Flash-style causal MQA attention (R10/R12 proven best: 512 uniform paired
// blocks = 2 blocks/CU, 4 waves x 16 q-rows, single-buffer staging,
// fixed-max softmax, native bf16 cvt, diagonal-only mask, Ps stride 68,
// setprio around MFMA).
// ---------------------------------------------------------------------------
__global__ __launch_bounds__(256) void flash_mfma(const ushort* __restrict__ qb,
                                                  const ushort* __restrict__ kb,
                                                  const ushort* __restrict__ vt,
                                                  ushort* __restrict__ aob) {
    __shared__ ushort Ks[64 * 128];    // 16 KB, swizzled 16B chunks
    __shared__ ushort VTs[128 * 64];   // 16 KB, swizzled 16B chunks
    __shared__ ushort Ps[4][16][68];   // 8.5 KB, per-wave P buffer

    const int tid = threadIdx.x;
    const int w = tid >> 6, lane = tid & 63;
    const int col = lane & 15, quad = lane >> 4;
    const int pairIdx = blockIdx.x, bh = blockIdx.y;
    const int b = bh >> 4, h = bh & 15;
    const int sel = col & 7;
    const float scl2 = 0.08838834764831845f * 1.44269504088896340736f;
    const float M2 = 11.5f * 1.44269504088896340736f;

    const int ksr[4] = {(tid + 0) >> 4, (tid + 256) >> 4, (tid + 512) >> 4,
                        (tid + 768) >> 4};
    const int vsr[4] = {(tid + 0) >> 3, (tid + 256) >> 3, (tid + 512) >> 3,
                        (tid + 768) >> 3};

    for (int sp = 0; sp < 2; ++sp) {
        const int qt = sp ? (31 - pairIdx) : pairIdx;
        const int q0 = qt * 64;

        const ushort* qrow =
            qb + ((size_t)(b * LL + q0 + w * 16 + col) * NH + h) * HD;
        short8 aq[4];
#pragma unroll
        for (int kc = 0; kc < 4; ++kc)
            aq[kc] = *reinterpret_cast<const short8*>(qrow + kc * 32 + quad * 8);

        float lrow[4] = {0.f, 0.f, 0.f, 0.f};
        floatx4 oacc[8];
#pragma unroll
        for (int dt = 0; dt < 8; ++dt) oacc[dt] = (floatx4){0.f, 0.f, 0.f, 0.f};

        const int ntiles = qt + 1;
        for (int kt = 0; kt < ntiles; ++kt) {
            const int k0 = kt * 64;
            __syncthreads();
#pragma unroll
            for (int rep = 0; rep < 4; ++rep) {
                int slot = tid + rep * 256;
                int r = ksr[rep];
                int gc = (slot & 15) ^ (r & 7);
                GL16(kb + (size_t)(b * LL + k0 + r) * HD + gc * 8,
                     Ks + (size_t)slot * 8);
            }
#pragma unroll
            for (int rep = 0; rep < 4; ++rep) {
                int slot = tid + rep * 256;
                int r = vsr[rep];
                int gc = (slot & 7) ^ (r & 7);
                GL16(vt + (size_t)(b * HD + r) * LL + k0 + gc * 8,
                     VTs + (size_t)slot * 8);
            }
            __syncthreads();

            floatx4 sacc[4];
#pragma unroll
            for (int nt = 0; nt < 4; ++nt)
                sacc[nt] = (floatx4){0.f, 0.f, 0.f, 0.f};
            __builtin_amdgcn_s_setprio(1);
#pragma unroll
            for (int nt = 0; nt < 4; ++nt) {
#pragma unroll
                for (int kc = 0; kc < 4; ++kc) {
                    short8 bk = *reinterpret_cast<const short8*>(
                        &Ks[(nt * 16 + col) * 128 +
                            ((kc * 4 + quad) ^ sel) * 8]);
                    sacc[nt] = __builtin_amdgcn_mfma_f32_16x16x32_bf16(
                        aq[kc], bk, sacc[nt], 0, 0, 0);
                }
            }
            __builtin_amdgcn_s_setprio(0);

            float psum[4] = {0.f, 0.f, 0.f, 0.f};
            if (kt == qt) {
#pragma unroll
                for (int nt = 0; nt < 4; ++nt) {
                    int kj = k0 + nt * 16 + col;
#pragma unroll
                    for (int rr = 0; rr < 4; ++rr) {
                        int qi = q0 + w * 16 + quad * 4 + rr;
                        float p = exp2f(fmaf(sacc[nt][rr], scl2, -M2));
                        p = (kj <= qi) ? p : 0.0f;
                        sacc[nt][rr] = p;
                        psum[rr] += p;
                    }
                }
            } else {
#pragma unroll
                for (int nt = 0; nt < 4; ++nt)
#pragma unroll
                    for (int rr = 0; rr < 4; ++rr) {
                        float p = exp2f(fmaf(sacc[nt][rr], scl2, -M2));
                        sacc[nt][rr] = p;
                        psum[rr] += p;
                    }
            }
#pragma unroll
            for (int rr = 0; rr < 4; ++rr) lrow[rr] += psum[rr];

#pragma unroll
            for (int nt = 0; nt < 4; ++nt)
#pragma unroll
                for (int rr = 0; rr < 4; ++rr)
                    Ps[w][quad * 4 + rr][nt * 16 + col] =
                        f2bf_fast(sacc[nt][rr]);
            asm volatile("s_waitcnt lgkmcnt(0)" ::: "memory");

#pragma unroll
            for (int kt2 = 0; kt2 < 2; ++kt2) {
                short8 ap = *reinterpret_cast<const short8*>(
                    &Ps[w][col][kt2 * 32 + quad * 8]);
                __builtin_amdgcn_s_setprio(1);
#pragma unroll
                for (int dt = 0; dt < 8; ++dt) {
                    short8 bv = *reinterpret_cast<const short8*>(
                        &VTs[(dt * 16 + col) * 64 +
                             ((kt2 * 4 + quad) ^ sel) * 8]);
                    oacc[dt] = __builtin_amdgcn_mfma_f32_16x16x32_bf16(
                        ap, bv, oacc[dt], 0, 0, 0);
                }
                __builtin_amdgcn_s_setprio(0);
            }
        }

#pragma unroll
        for (int off = 1; off < 16; off <<= 1)
#pragma unroll
            for (int rr = 0; rr < 4; ++rr)
                lrow[rr] += __shfl_xor(lrow[rr], off);
        float inv[4];
#pragma unroll
        for (int rr = 0; rr < 4; ++rr) inv[rr] = 1.0f / lrow[rr];
#pragma unroll
        for (int dt = 0; dt < 8; ++dt)
#pragma unroll
            for (int rr = 0; rr < 4; ++rr)
                aob[((size_t)(b * LL + q0 + w * 16 + quad * 4 + rr) * NH + h) *
                        HD + dt * 16 + col] =
                    f2bf_fast(oacc[dt][rr] * inv[rr]);
    }
}

// ---------------------------------------------------------------------------
extern "C" void kernel_launch(void* const* d_in, const int* in_sizes, int n_in,
                              void* d_out, int out_size, void* d_ws,
                              size_t ws_size, hipStream_t stream) {
    const float* x    = (const float*)d_in[0];
    const float* cosb = (const float*)d_in[1];
    const float* sinb = (const float*)d_in[2];
    const float* Wq   = (const float*)d_in[3];
    const float* Wk   = (const float*)d_in[4];
    const float* Wv   = (const float*)d_in[5];
    const float* Wo   = (const float*)d_in[6];
    float* out = (float*)d_out;

    float* qkv  = (float*)d_ws;                         // M*2304 f32
    ushort* xb  = (ushort*)(qkv + (size_t)MROWS * NKV); // M*DIM bf16
    ushort* qb  = xb + (size_t)MROWS * DIM;             // M*DIM bf16
    ushort* kb  = qb + (size_t)MROWS * DIM;             // M*HD bf16
    ushort* vt  = kb + (size_t)MROWS * HD;              // M*HD bf16 (B,D,L)
    ushort* aob = vt + (size_t)MROWS * HD;              // M*DIM bf16
    ushort* Wcatt = aob + (size_t)MROWS * DIM;          // 2304*2048 bf16
    ushort* Wot   = Wcatt + (size_t)NKV * DIM;          // 2048*2048 bf16

    // fused input-cast + weight prep
    prep<<<dim3(4096 + 2176), 256, 0, stream>>>(x, xb, Wq, Wk, Wv, Wo, Wcatt,
                                                Wot);

    // fused q|k|v projection: (M,2048) @ (2048,2304), 256x144 full-coverage
    gemm2pq<<<dim3(NKV / 144, MROWS / 256), 512, 0, stream>>>(xb, Wcatt, qkv,
                                                              NKV);

    // fused RoPE+RMSNorm (q,k) + V transpose
    rope_vt<<<dim3(16384 + 1024 + 128), 256, 0, stream>>>(qkv, qb, kb, vt,
                                                          cosb, sinb);

    // causal MQA attention: 512 uniform paired blocks (qt, 31-qt)
    flash_mfma<<<dim3(LL / 128, BB * NH), 256, 0, stream>>>(qb, kb, vt, aob);

    // output projection: (M,2048) @ (2048,2048), 128x256 + XCD swz
    gemm2pw<<<dim3(DIM / 256, MROWS / 128), 512, 0, stream>>>(aob, Wot, out,
                                                              DIM);
}